// Round 1
// baseline (1341.808 us; speedup 1.0000x reference)
//
#include <hip/hip_runtime.h>

#define HD 64  // hidden dim

// ---------------------------------------------------------------------------
// zero-fill ints
// ---------------------------------------------------------------------------
__global__ void __launch_bounds__(256) zero_int_kernel(int* p, long n) {
    long i = blockIdx.x * (long)blockDim.x + threadIdx.x;
    long stride = (long)gridDim.x * blockDim.x;
    for (; i < n; i += stride) p[i] = 0;
}

// ---------------------------------------------------------------------------
// histogram of dst into cnt
// ---------------------------------------------------------------------------
__global__ void __launch_bounds__(256) hist_kernel(const int* __restrict__ dst,
                                                   int* __restrict__ cnt, long E) {
    long i = blockIdx.x * (long)blockDim.x + threadIdx.x;
    long stride = (long)gridDim.x * blockDim.x;
    for (; i < E; i += stride) atomicAdd(&cnt[dst[i]], 1);
}

// ---------------------------------------------------------------------------
// scan stage 1: per-256-chunk sums
// ---------------------------------------------------------------------------
__global__ void __launch_bounds__(256) blocksum_kernel(const int* __restrict__ cnt,
                                                       int* __restrict__ bsum, int N) {
    int i = blockIdx.x * 256 + threadIdx.x;
    int v = (i < N) ? cnt[i] : 0;
    #pragma unroll
    for (int off = 32; off; off >>= 1) v += __shfl_down(v, off, 64);
    __shared__ int s[4];
    if ((threadIdx.x & 63) == 0) s[threadIdx.x >> 6] = v;
    __syncthreads();
    if (threadIdx.x == 0) bsum[blockIdx.x] = s[0] + s[1] + s[2] + s[3];
}

// ---------------------------------------------------------------------------
// scan stage 2: single block scans the (<=512) chunk sums -> exclusive bpre
// ---------------------------------------------------------------------------
__global__ void __launch_bounds__(512) scan2_kernel(const int* __restrict__ bsum,
                                                    int* __restrict__ bpre,
                                                    int* __restrict__ offs,
                                                    int nb, int N, int E) {
    __shared__ int s[512];
    int tid = threadIdx.x;
    int v = (tid < nb) ? bsum[tid] : 0;
    s[tid] = v;
    __syncthreads();
    for (int off = 1; off < 512; off <<= 1) {
        int add = (tid >= off) ? s[tid - off] : 0;
        __syncthreads();
        s[tid] += add;
        __syncthreads();
    }
    if (tid < nb) bpre[tid] = s[tid] - v;  // exclusive
    if (tid == 0) offs[N] = E;
}

// ---------------------------------------------------------------------------
// scan stage 3: per-chunk exclusive scan + chunk prefix -> offs, cursor
// ---------------------------------------------------------------------------
__global__ void __launch_bounds__(256) scan3_kernel(const int* __restrict__ cnt,
                                                    const int* __restrict__ bpre,
                                                    int* __restrict__ offs,
                                                    int* __restrict__ cursor, int N) {
    __shared__ int s[256];
    int tid = threadIdx.x;
    int i = blockIdx.x * 256 + tid;
    int v = (i < N) ? cnt[i] : 0;
    s[tid] = v;
    __syncthreads();
    for (int off = 1; off < 256; off <<= 1) {
        int add = (tid >= off) ? s[tid - off] : 0;
        __syncthreads();
        s[tid] += add;
        __syncthreads();
    }
    if (i < N) {
        int excl = s[tid] - v + bpre[blockIdx.x];
        offs[i] = excl;
        cursor[i] = excl;
    }
}

// ---------------------------------------------------------------------------
// fill permutation: for each edge, place its id and src into CSR slot
// ---------------------------------------------------------------------------
__global__ void __launch_bounds__(256) fill_kernel(const int* __restrict__ src,
                                                   const int* __restrict__ dst,
                                                   int* __restrict__ cursor,
                                                   int* __restrict__ perm,
                                                   int* __restrict__ sp, long E) {
    long i = blockIdx.x * (long)blockDim.x + threadIdx.x;
    long stride = (long)gridDim.x * blockDim.x;
    for (; i < E; i += stride) {
        int d = dst[i];
        int p = atomicAdd(&cursor[d], 1);
        perm[p] = (int)i;
        sp[p]   = src[i];
    }
}

// ---------------------------------------------------------------------------
// node init: h = relu([emb[z], t] @ rw1 + rb1) @ rw2 + rb2
// TWO nodes per wave: each weight ds_read feeds 2 fma chains (2x ILP,
// half the LDS weight traffic per node). s_x rows reused for hidden layer.
// Per-wave-private LDS slices; no inner barriers.
// ---------------------------------------------------------------------------
__global__ void __launch_bounds__(512, 6) node_init_kernel(
    const int* __restrict__ z, const float* __restrict__ t,
    const float* __restrict__ emb,
    const float* __restrict__ rw1, const float* __restrict__ rb1,
    const float* __restrict__ rw2, const float* __restrict__ rb2,
    float* __restrict__ h, int N)
{
    __shared__ float s_w1[65 * 64];
    __shared__ float s_w2[64 * 64];
    __shared__ float s_x[16][66];   // 2 rows per wave; [64]=t slot

    int tid = threadIdx.x;
    for (int i = tid; i < 65 * 64; i += 512) s_w1[i] = rw1[i];
    for (int i = tid; i < 64 * 64; i += 512) s_w2[i] = rw2[i];
    __syncthreads();

    int wv  = tid >> 6;   // 0..7
    int c   = tid & 63;
    int wv2 = wv << 1;
    float b1 = rb1[c];
    float b2 = rb2[c];

    long stride = (long)gridDim.x * 16;
    for (long base = (long)blockIdx.x * 16; base < N; base += stride) {
        long node0 = base + (long)wv2;
        if (node0 >= N) continue;
        long node1 = node0 + 1;
        bool v1 = (node1 < N);

        s_x[wv2][c] = emb[(long)z[node0] * HD + c];
        if (c == 0) s_x[wv2][64] = t[node0];
        if (v1) {
            s_x[wv2 + 1][c] = emb[(long)z[node1] * HD + c];
            if (c == 0) s_x[wv2 + 1][64] = t[node1];
        }

        float a10 = b1, a11 = b1;
        #pragma unroll
        for (int k = 0; k < 65; ++k) {
            float w = s_w1[k * 64 + c];
            a10 = fmaf(s_x[wv2][k],     w, a10);
            a11 = fmaf(s_x[wv2 + 1][k], w, a11);
        }
        // reuse s_x rows for hidden activations (in-wave ordered via lgkmcnt)
        s_x[wv2][c]     = fmaxf(a10, 0.f);
        s_x[wv2 + 1][c] = fmaxf(a11, 0.f);

        float a20 = b2, a21 = b2;
        #pragma unroll
        for (int k = 0; k < 64; ++k) {
            float w = s_w2[k * 64 + c];
            a20 = fmaf(s_x[wv2][k],     w, a20);
            a21 = fmaf(s_x[wv2 + 1][k], w, a21);
        }
        h[node0 * HD + c] = a20;
        if (v1) h[node1 * HD + c] = a21;
    }
}

// ---------------------------------------------------------------------------
// fused layer, TWO nodes per wave.
// Aggregation: fused edge loop over both nodes (4 edges x 16 lanes x float4
// per node per iter => up to 4KB in flight per wave), indices prefetched one
// iteration ahead. Cross-lane shfl_xor reduction for both accumulators.
// MLP: both nodes share every weight ds_read (2 fma chains per read).
// s_x rows reused for hidden layer. NO block barriers in the node loop.
// ---------------------------------------------------------------------------
__global__ void __launch_bounds__(512, 6) layer_kernel(
    const int* __restrict__ offs, const int* __restrict__ perm,
    const int* __restrict__ sp,
    const float* __restrict__ h, const float* __restrict__ ea,
    const float* __restrict__ w1, const float* __restrict__ b1,
    const float* __restrict__ w2, const float* __restrict__ b2,
    float* __restrict__ out, int N, int relu_flag)
{
    __shared__ float s_w1[64 * 64];
    __shared__ float s_w2[64 * 64];
    __shared__ float s_x[16][64];   // 2 rows per wave (agg, then hidden act)

    int tid = threadIdx.x;
    for (int i = tid; i < 64 * 64; i += 512) {
        s_w1[i] = w1[i];
        s_w2[i] = w2[i];
    }
    __syncthreads();

    int wv   = tid >> 6;        // wave in block: 0..7
    int lane = tid & 63;
    int c    = lane;            // channel (MLP phase)
    int eg   = lane >> 4;       // edge group 0..3
    int cq   = (lane & 15) * 4; // channel-quad base (agg phase)
    int wv2  = wv << 1;
    float bb1 = b1[c];
    float bb2 = b2[c];

    long stride = (long)gridDim.x * 16;
    for (long base = (long)blockIdx.x * 16; base < N; base += stride) {
        long node0 = base + (long)wv2;
        if (node0 >= N) continue;
        long node1 = node0 + 1;
        bool v1 = (node1 < N);

        int jb0 = offs[node0], je0 = offs[node0 + 1];
        int jb1 = 0, je1 = 0;
        float hval0 = h[node0 * HD + c];
        float hval1 = 0.f;
        if (v1) {
            jb1 = offs[node1]; je1 = offs[node1 + 1];
            hval1 = h[node1 * HD + c];
        }

        float4 acc0; acc0.x = acc0.y = acc0.z = acc0.w = 0.f;
        float4 acc1 = acc0;
        int j0 = jb0 + eg, j1 = jb1 + eg;
        int e0 = 0, s0 = 0, e1 = 0, s1 = 0;
        if (j0 < je0) { e0 = perm[j0]; s0 = sp[j0]; }
        if (j1 < je1) { e1 = perm[j1]; s1 = sp[j1]; }
        while (j0 < je0 || j1 < je1) {
            bool p0 = j0 < je0, p1 = j1 < je1;
            const float4 av0 = *(const float4*)(ea + (long)e0 * HD + cq);
            const float4 hv0 = *(const float4*)(h  + (long)s0 * HD + cq);
            const float4 av1 = *(const float4*)(ea + (long)e1 * HD + cq);
            const float4 hv1 = *(const float4*)(h  + (long)s1 * HD + cq);
            int jn0 = j0 + 4, jn1 = j1 + 4;
            int en0 = e0, sn0 = s0, en1 = e1, sn1 = s1;
            if (jn0 < je0) { en0 = perm[jn0]; sn0 = sp[jn0]; }   // prefetch next
            if (jn1 < je1) { en1 = perm[jn1]; sn1 = sp[jn1]; }
            if (p0) {
                acc0.x += fmaxf(av0.x + hv0.x, 0.f);
                acc0.y += fmaxf(av0.y + hv0.y, 0.f);
                acc0.z += fmaxf(av0.z + hv0.z, 0.f);
                acc0.w += fmaxf(av0.w + hv0.w, 0.f);
            }
            if (p1) {
                acc1.x += fmaxf(av1.x + hv1.x, 0.f);
                acc1.y += fmaxf(av1.y + hv1.y, 0.f);
                acc1.z += fmaxf(av1.z + hv1.z, 0.f);
                acc1.w += fmaxf(av1.w + hv1.w, 0.f);
            }
            j0 = jn0; j1 = jn1;
            e0 = en0; s0 = sn0; e1 = en1; s1 = sn1;
        }
        // reduce the 4 edge groups (lanes l, l^16, l^32, l^48 share cq)
        #pragma unroll
        for (int m = 16; m <= 32; m <<= 1) {
            acc0.x += __shfl_xor(acc0.x, m, 64);
            acc0.y += __shfl_xor(acc0.y, m, 64);
            acc0.z += __shfl_xor(acc0.z, m, 64);
            acc0.w += __shfl_xor(acc0.w, m, 64);
            acc1.x += __shfl_xor(acc1.x, m, 64);
            acc1.y += __shfl_xor(acc1.y, m, 64);
            acc1.z += __shfl_xor(acc1.z, m, 64);
            acc1.w += __shfl_xor(acc1.w, m, 64);
        }
        if (lane < 32) {
            float4 a = (lane < 16) ? acc0 : acc1;
            *(float4*)&s_x[wv2 + (lane >> 4)][cq] = a;
        }
        // add self term (agg = sum + h[n]); in-wave LDS ordering via waitcnt
        s_x[wv2][c]     += hval0;
        s_x[wv2 + 1][c] += hval1;

        float a10 = bb1, a11 = bb1;
        #pragma unroll
        for (int k = 0; k < 64; ++k) {
            float w = s_w1[k * 64 + c];
            a10 = fmaf(s_x[wv2][k],     w, a10);
            a11 = fmaf(s_x[wv2 + 1][k], w, a11);
        }
        // reuse s_x rows for hidden activations
        s_x[wv2][c]     = fmaxf(a10, 0.f);
        s_x[wv2 + 1][c] = fmaxf(a11, 0.f);

        float a20 = bb2, a21 = bb2;
        #pragma unroll
        for (int k = 0; k < 64; ++k) {
            float w = s_w2[k * 64 + c];
            a20 = fmaf(s_x[wv2][k],     w, a20);
            a21 = fmaf(s_x[wv2 + 1][k], w, a21);
        }
        if (relu_flag) { a20 = fmaxf(a20, 0.f); a21 = fmaxf(a21, 0.f); }
        out[node0 * HD + c] = a20 + hval0;
        if (v1) out[node1 * HD + c] = a21 + hval1;
    }
}

// ---------------------------------------------------------------------------
extern "C" void kernel_launch(void* const* d_in, const int* in_sizes, int n_in,
                              void* d_out, int out_size, void* d_ws, size_t ws_size,
                              hipStream_t stream)
{
    const int*   z    = (const int*)  d_in[0];
    const int*   ei   = (const int*)  d_in[1];
    const float* ea   = (const float*)d_in[2];
    const float* t    = (const float*)d_in[3];
    const float* emb  = (const float*)d_in[4];
    const float* rw1  = (const float*)d_in[5];
    const float* rb1  = (const float*)d_in[6];
    const float* rw2  = (const float*)d_in[7];
    const float* rb2  = (const float*)d_in[8];
    const float* cw1  = (const float*)d_in[9];
    const float* cb1  = (const float*)d_in[10];
    const float* cw2  = (const float*)d_in[11];
    const float* cb2  = (const float*)d_in[12];

    int  N = in_sizes[0];
    long E = (long)in_sizes[1] / 2;
    const int* src = ei;        // edge_index[0]
    const int* dst = ei + E;    // edge_index[1]

    float* out = (float*)d_out;

    // workspace layout
    float* bufA   = (float*)d_ws;                 // N*HD floats
    int*   offs   = (int*)(bufA + (long)N * HD);  // N+1
    int*   cursor = offs + (N + 1);               // N
    int*   perm   = cursor + N;                   // E
    int*   sp     = perm + E;                     // E
    int*   bsum   = sp + E;                       // nb
    int    nb     = (N + 255) / 256;
    int*   bpre   = bsum + nb;                    // nb

    // --- build CSR-by-dst index ---
    zero_int_kernel<<<256, 256, 0, stream>>>(cursor, N);
    hist_kernel<<<2048, 256, 0, stream>>>(dst, cursor, E);
    blocksum_kernel<<<nb, 256, 0, stream>>>(cursor, bsum, N);
    scan2_kernel<<<1, 512, 0, stream>>>(bsum, bpre, offs, nb, N, (int)E);
    scan3_kernel<<<nb, 256, 0, stream>>>(cursor, bpre, offs, cursor, N);
    fill_kernel<<<2048, 256, 0, stream>>>(src, dst, cursor, perm, sp, E);

    // --- h0 = init MLP ---
    node_init_kernel<<<1024, 512, 0, stream>>>(z, t, emb, rw1, rb1, rw2, rb2,
                                               bufA, N);

    // --- 3 GINE layers, ping-pong bufA <-> d_out ---
    float* hcur = bufA;
    for (int li = 0; li < 3; ++li) {
        float* hout = (li == 1) ? bufA : out;  // d_out, bufA, d_out
        layer_kernel<<<1024, 512, 0, stream>>>(
            offs, perm, sp, hcur, ea,
            cw1 + (long)li * HD * HD, cb1 + (long)li * HD,
            cw2 + (long)li * HD * HD, cb2 + (long)li * HD,
            hout, N, (li < 2) ? 1 : 0);
        hcur = hout;
    }
}

// Round 3
// 1248.698 us; speedup vs baseline: 1.0746x; 1.0746x over previous
//
#include <hip/hip_runtime.h>

#define HD 64  // hidden dim

// ---------------------------------------------------------------------------
// zero-fill ints
// ---------------------------------------------------------------------------
__global__ void __launch_bounds__(256) zero_int_kernel(int* p, long n) {
    long i = blockIdx.x * (long)blockDim.x + threadIdx.x;
    long stride = (long)gridDim.x * blockDim.x;
    for (; i < n; i += stride) p[i] = 0;
}

// ---------------------------------------------------------------------------
// histogram of dst into cnt
// ---------------------------------------------------------------------------
__global__ void __launch_bounds__(256) hist_kernel(const int* __restrict__ dst,
                                                   int* __restrict__ cnt, long E) {
    long i = blockIdx.x * (long)blockDim.x + threadIdx.x;
    long stride = (long)gridDim.x * blockDim.x;
    for (; i < E; i += stride) atomicAdd(&cnt[dst[i]], 1);
}

// ---------------------------------------------------------------------------
// scan stage 1: per-256-chunk sums
// ---------------------------------------------------------------------------
__global__ void __launch_bounds__(256) blocksum_kernel(const int* __restrict__ cnt,
                                                       int* __restrict__ bsum, int N) {
    int i = blockIdx.x * 256 + threadIdx.x;
    int v = (i < N) ? cnt[i] : 0;
    #pragma unroll
    for (int off = 32; off; off >>= 1) v += __shfl_down(v, off, 64);
    __shared__ int s[4];
    if ((threadIdx.x & 63) == 0) s[threadIdx.x >> 6] = v;
    __syncthreads();
    if (threadIdx.x == 0) bsum[blockIdx.x] = s[0] + s[1] + s[2] + s[3];
}

// ---------------------------------------------------------------------------
// scan stage 2: single block scans the (<=512) chunk sums -> exclusive bpre
// ---------------------------------------------------------------------------
__global__ void __launch_bounds__(512) scan2_kernel(const int* __restrict__ bsum,
                                                    int* __restrict__ bpre,
                                                    int* __restrict__ offs,
                                                    int nb, int N, int E) {
    __shared__ int s[512];
    int tid = threadIdx.x;
    int v = (tid < nb) ? bsum[tid] : 0;
    s[tid] = v;
    __syncthreads();
    for (int off = 1; off < 512; off <<= 1) {
        int add = (tid >= off) ? s[tid - off] : 0;
        __syncthreads();
        s[tid] += add;
        __syncthreads();
    }
    if (tid < nb) bpre[tid] = s[tid] - v;  // exclusive
    if (tid == 0) offs[N] = E;
}

// ---------------------------------------------------------------------------
// scan stage 3: per-chunk exclusive scan + chunk prefix -> offs, cursor
// ---------------------------------------------------------------------------
__global__ void __launch_bounds__(256) scan3_kernel(const int* __restrict__ cnt,
                                                    const int* __restrict__ bpre,
                                                    int* __restrict__ offs,
                                                    int* __restrict__ cursor, int N) {
    __shared__ int s[256];
    int tid = threadIdx.x;
    int i = blockIdx.x * 256 + tid;
    int v = (i < N) ? cnt[i] : 0;
    s[tid] = v;
    __syncthreads();
    for (int off = 1; off < 256; off <<= 1) {
        int add = (tid >= off) ? s[tid - off] : 0;
        __syncthreads();
        s[tid] += add;
        __syncthreads();
    }
    if (i < N) {
        int excl = s[tid] - v + bpre[blockIdx.x];
        offs[i] = excl;
        cursor[i] = excl;
    }
}

// ---------------------------------------------------------------------------
// fill permutation: for each edge, place its id and src into CSR slot
// ---------------------------------------------------------------------------
__global__ void __launch_bounds__(256) fill_kernel(const int* __restrict__ src,
                                                   const int* __restrict__ dst,
                                                   int* __restrict__ cursor,
                                                   int* __restrict__ perm,
                                                   int* __restrict__ sp, long E) {
    long i = blockIdx.x * (long)blockDim.x + threadIdx.x;
    long stride = (long)gridDim.x * blockDim.x;
    for (; i < E; i += stride) {
        int d = dst[i];
        int p = atomicAdd(&cursor[d], 1);
        perm[p] = (int)i;
        sp[p]   = src[i];
    }
}

// ---------------------------------------------------------------------------
// Weight swizzle helper (store side), shared convention:
// transposed wT[c][k] stored at dword index  c*64 + ((q ^ (c&7))<<2) + r
// with q = k>>2, r = k&3. Read side: lane c reads float4 at
// c*64 + ((q ^ (c&7))<<2)  -> covers k = 4q..4q+3 of column c.
// Per 8-lane group the XOR makes the 8 16B slots distinct within each
// 128B bank frame -> structural-minimum (full-BW) LDS access.
// ---------------------------------------------------------------------------

// ---------------------------------------------------------------------------
// node init: h = relu([emb[z], t] @ rw1 + rb1) @ rw2 + rb2
// One node per wave. Layer-1 input read directly from emb (25.6KB, L1-hot)
// via wave-uniform float4 broadcasts; weights transposed+swizzled in LDS,
// read as ds_read_b128. 4 partial accumulators per dot product.
// ---------------------------------------------------------------------------
__global__ void __launch_bounds__(512, 6) node_init_kernel(
    const int* __restrict__ z, const float* __restrict__ t,
    const float* __restrict__ emb,
    const float* __restrict__ rw1, const float* __restrict__ rb1,
    const float* __restrict__ rw2, const float* __restrict__ rb2,
    float* __restrict__ h, int N)
{
    __shared__ float s_w1[64 * 64];   // transposed+swizzled rows k=0..63
    __shared__ float s_w1b[64];       // t row (k=64)
    __shared__ float s_w2[64 * 64];   // transposed+swizzled
    __shared__ float s_y1[8][64];     // hidden activations, one row per wave

    int tid = threadIdx.x;
    for (int i = tid; i < 65 * 64; i += 512) {
        int k = i >> 6, cc = i & 63;
        if (k < 64) {
            int q = k >> 2, r = k & 3;
            s_w1[(cc << 6) + ((q ^ (cc & 7)) << 2) + r] = rw1[i];
        } else {
            s_w1b[cc] = rw1[i];
        }
    }
    for (int i = tid; i < 64 * 64; i += 512) {
        int k = i >> 6, cc = i & 63;
        int q = k >> 2, r = k & 3;
        s_w2[(cc << 6) + ((q ^ (cc & 7)) << 2) + r] = rw2[i];
    }
    __syncthreads();

    int wv = tid >> 6;   // 0..7
    int c  = tid & 63;
    int wbase = c << 6;
    int wsel  = (c & 7) << 2;
    float b1 = rb1[c];
    float b2 = rb2[c];

    long stride = (long)gridDim.x * 8;
    for (long base = (long)blockIdx.x * 8; base < N; base += stride) {
        long node = base + wv;
        if (node >= N) continue;

        int   zi = z[node];           // wave-uniform
        float tv = t[node];
        const float* xrow = emb + (long)zi * HD;

        float a0 = b1, a1 = 0.f, a2 = 0.f, a3 = 0.f;
        #pragma unroll
        for (int q = 0; q < 16; ++q) {
            const float4 xq = *(const float4*)(xrow + (q << 2));
            const float4 wq = *(const float4*)&s_w1[wbase + (((q << 2) ^ wsel))];
            a0 = fmaf(xq.x, wq.x, a0);
            a1 = fmaf(xq.y, wq.y, a1);
            a2 = fmaf(xq.z, wq.z, a2);
            a3 = fmaf(xq.w, wq.w, a3);
        }
        float acc1 = (a0 + a1) + (a2 + a3) + tv * s_w1b[c];
        s_y1[wv][c] = fmaxf(acc1, 0.f);

        float d0 = b2, d1 = 0.f, d2 = 0.f, d3 = 0.f;
        #pragma unroll
        for (int q = 0; q < 16; ++q) {
            const float4 xq = *(const float4*)&s_y1[wv][q << 2];
            const float4 wq = *(const float4*)&s_w2[wbase + (((q << 2) ^ wsel))];
            d0 = fmaf(xq.x, wq.x, d0);
            d1 = fmaf(xq.y, wq.y, d1);
            d2 = fmaf(xq.z, wq.z, d2);
            d3 = fmaf(xq.w, wq.w, d3);
        }
        h[node * HD + c] = (d0 + d1) + (d2 + d3);
    }
}

// ---------------------------------------------------------------------------
// fused layer. One node per wave (reverted from 2-node fusion, which wasted
// ~30% gather traffic on predicated-off loads). Aggregation identical to the
// 1129us version: 4 edges x 16 lanes x float4, index prefetch, shfl_xor
// reduction. MLP rebuilt: transposed+swizzled weights in LDS read as
// ds_read_b128 (4x payload per LDS instruction), x via wave-uniform float4
// broadcasts, 4 partial accumulators. NO block barriers in the node loop.
// ---------------------------------------------------------------------------
__global__ void __launch_bounds__(512, 6) layer_kernel(
    const int* __restrict__ offs, const int* __restrict__ perm,
    const int* __restrict__ sp,
    const float* __restrict__ h, const float* __restrict__ ea,
    const float* __restrict__ w1, const float* __restrict__ b1,
    const float* __restrict__ w2, const float* __restrict__ b2,
    float* __restrict__ out, int N, int relu_flag)
{
    __shared__ float s_w1[64 * 64];   // transposed+swizzled
    __shared__ float s_w2[64 * 64];   // transposed+swizzled
    __shared__ float s_x[8][64];      // agg vector, one row per wave
    __shared__ float s_y1[8][64];     // hidden activation

    int tid = threadIdx.x;
    for (int i = tid; i < 64 * 64; i += 512) {
        int k = i >> 6, cc = i & 63;
        int q = k >> 2, r = k & 3;
        int idx = (cc << 6) + ((q ^ (cc & 7)) << 2) + r;
        s_w1[idx] = w1[i];
        s_w2[idx] = w2[i];
    }
    __syncthreads();

    int wv   = tid >> 6;        // wave in block: 0..7
    int lane = tid & 63;
    int c    = lane;            // channel (MLP phase)
    int eg   = lane >> 4;       // edge group 0..3
    int cq   = (lane & 15) * 4; // channel-quad base (agg phase)
    int wbase = c << 6;
    int wsel  = (c & 7) << 2;
    float bb1 = b1[c];
    float bb2 = b2[c];

    long stride = (long)gridDim.x * 8;
    for (long base = (long)blockIdx.x * 8; base < N; base += stride) {
        long node = base + wv;
        if (node >= N) continue;

        int jb = offs[node], je = offs[node + 1];
        float hval = h[node * HD + c];      // residual + self term

        float4 acc; acc.x = acc.y = acc.z = acc.w = 0.f;
        int j = jb + eg;
        int e = 0, s = 0;
        if (j < je) { e = perm[j]; s = sp[j]; }
        while (j < je) {
            const float4 av = *(const float4*)(ea + (long)e * HD + cq);
            const float4 hv = *(const float4*)(h  + (long)s * HD + cq);
            int jn = j + 4;
            int en = 0, sn = 0;
            if (jn < je) { en = perm[jn]; sn = sp[jn]; }   // prefetch next
            acc.x += fmaxf(av.x + hv.x, 0.f);
            acc.y += fmaxf(av.y + hv.y, 0.f);
            acc.z += fmaxf(av.z + hv.z, 0.f);
            acc.w += fmaxf(av.w + hv.w, 0.f);
            j = jn; e = en; s = sn;
        }
        // reduce the 4 edge groups (lanes l, l^16, l^32, l^48 share cq)
        #pragma unroll
        for (int m = 16; m <= 32; m <<= 1) {
            acc.x += __shfl_xor(acc.x, m, 64);
            acc.y += __shfl_xor(acc.y, m, 64);
            acc.z += __shfl_xor(acc.z, m, 64);
            acc.w += __shfl_xor(acc.w, m, 64);
        }
        if (lane < 16) *(float4*)&s_x[wv][cq] = acc;
        // add self term (agg = sum + h[n]); in-wave LDS ordering via waitcnt
        s_x[wv][c] += hval;

        float a0 = bb1, a1 = 0.f, a2 = 0.f, a3 = 0.f;
        #pragma unroll
        for (int q = 0; q < 16; ++q) {
            const float4 xq = *(const float4*)&s_x[wv][q << 2];
            const float4 wq = *(const float4*)&s_w1[wbase + (((q << 2) ^ wsel))];
            a0 = fmaf(xq.x, wq.x, a0);
            a1 = fmaf(xq.y, wq.y, a1);
            a2 = fmaf(xq.z, wq.z, a2);
            a3 = fmaf(xq.w, wq.w, a3);
        }
        float h1 = (a0 + a1) + (a2 + a3);
        s_y1[wv][c] = fmaxf(h1, 0.f);

        float d0 = bb2, d1 = 0.f, d2 = 0.f, d3 = 0.f;
        #pragma unroll
        for (int q = 0; q < 16; ++q) {
            const float4 xq = *(const float4*)&s_y1[wv][q << 2];
            const float4 wq = *(const float4*)&s_w2[wbase + (((q << 2) ^ wsel))];
            d0 = fmaf(xq.x, wq.x, d0);
            d1 = fmaf(xq.y, wq.y, d1);
            d2 = fmaf(xq.z, wq.z, d2);
            d3 = fmaf(xq.w, wq.w, d3);
        }
        float a2f = (d0 + d1) + (d2 + d3);
        if (relu_flag) a2f = fmaxf(a2f, 0.f);
        out[node * HD + c] = a2f + hval;
    }
}

// ---------------------------------------------------------------------------
extern "C" void kernel_launch(void* const* d_in, const int* in_sizes, int n_in,
                              void* d_out, int out_size, void* d_ws, size_t ws_size,
                              hipStream_t stream)
{
    const int*   z    = (const int*)  d_in[0];
    const int*   ei   = (const int*)  d_in[1];
    const float* ea   = (const float*)d_in[2];
    const float* t    = (const float*)d_in[3];
    const float* emb  = (const float*)d_in[4];
    const float* rw1  = (const float*)d_in[5];
    const float* rb1  = (const float*)d_in[6];
    const float* rw2  = (const float*)d_in[7];
    const float* rb2  = (const float*)d_in[8];
    const float* cw1  = (const float*)d_in[9];
    const float* cb1  = (const float*)d_in[10];
    const float* cw2  = (const float*)d_in[11];
    const float* cb2  = (const float*)d_in[12];

    int  N = in_sizes[0];
    long E = (long)in_sizes[1] / 2;
    const int* src = ei;        // edge_index[0]
    const int* dst = ei + E;    // edge_index[1]

    float* out = (float*)d_out;

    // workspace layout
    float* bufA   = (float*)d_ws;                 // N*HD floats
    int*   offs   = (int*)(bufA + (long)N * HD);  // N+1
    int*   cursor = offs + (N + 1);               // N
    int*   perm   = cursor + N;                   // E
    int*   sp     = perm + E;                     // E
    int*   bsum   = sp + E;                       // nb
    int    nb     = (N + 255) / 256;
    int*   bpre   = bsum + nb;                    // nb

    // --- build CSR-by-dst index ---
    zero_int_kernel<<<256, 256, 0, stream>>>(cursor, N);
    hist_kernel<<<2048, 256, 0, stream>>>(dst, cursor, E);
    blocksum_kernel<<<nb, 256, 0, stream>>>(cursor, bsum, N);
    scan2_kernel<<<1, 512, 0, stream>>>(bsum, bpre, offs, nb, N, (int)E);
    scan3_kernel<<<nb, 256, 0, stream>>>(cursor, bpre, offs, cursor, N);
    fill_kernel<<<2048, 256, 0, stream>>>(src, dst, cursor, perm, sp, E);

    // --- h0 = init MLP ---
    node_init_kernel<<<1024, 512, 0, stream>>>(z, t, emb, rw1, rb1, rw2, rb2,
                                               bufA, N);

    // --- 3 GINE layers, ping-pong bufA <-> d_out ---
    float* hcur = bufA;
    for (int li = 0; li < 3; ++li) {
        float* hout = (li == 1) ? bufA : out;  // d_out, bufA, d_out
        layer_kernel<<<1024, 512, 0, stream>>>(
            offs, perm, sp, hcur, ea,
            cw1 + (long)li * HD * HD, cb1 + (long)li * HD,
            cw2 + (long)li * HD * HD, cb2 + (long)li * HD,
            hout, N, (li < 2) ? 1 : 0);
        hcur = hout;
    }
}